// Round 1
// baseline (115.298 us; speedup 1.0000x reference)
//
#include <hip/hip_runtime.h>
#include <stdint.h>

#define H_ 120
#define W_ 160
#define HW_ (H_*W_)          // 19200
#define SKIP_ 8
#define P_ (HW_/SKIP_)       // 2400 voting pixels
#define NC_ 8                // classes
#define THR2_ 0.81f          // 0.9^2
#define EPSV_ 1e-6f

typedef unsigned long long ull;

// ---------------- Kernel 1: preprocess + class-compact voting pixels ----------------
__global__ void k_prep(const int* __restrict__ labels, const int* __restrict__ masks,
                       const float* __restrict__ vp,
                       ull* __restrict__ best, float4* __restrict__ arr4,
                       float2* __restrict__ arr2, int* __restrict__ clsStart)
{
    int b = blockIdx.x;
    labels += (size_t)b * HW_;
    masks  += (size_t)b * HW_;
    vp     += (size_t)b * 3 * NC_ * HW_;
    float4* a4 = arr4 + (size_t)b * P_;
    float2* a2 = arr2 + (size_t)b * P_;

    __shared__ int s_cnt[NC_];
    __shared__ int s_off[NC_];
    __shared__ int s_start[NC_ + 1];
    int t = threadIdx.x;
    if (t < NC_) s_cnt[t] = 0;
    __syncthreads();
    for (int p = t; p < P_; p += blockDim.x) {
        int idx = p * SKIP_;
        int lab = labels[idx];
        if (masks[idx] > 0 && lab > 0) atomicAdd(&s_cnt[lab], 1);
    }
    __syncthreads();
    if (t == 0) {
        int acc = 0;
        for (int c = 0; c < NC_; ++c) { s_start[c] = acc; acc += s_cnt[c]; }
        s_start[NC_] = acc;
    }
    __syncthreads();
    if (t < NC_) s_off[t] = s_start[t];
    if (t < NC_ + 1) clsStart[b*(NC_+1) + t] = s_start[t];   // diffs == nvalid per class
    if (t < NC_) best[b*NC_ + t] = 0ULL;                     // init for atomicMax
    __syncthreads();
    for (int p = t; p < P_; p += blockDim.x) {
        int idx = p * SKIP_;
        int lab = labels[idx];
        if (masks[idx] > 0 && lab > 0) {
            float xs = (float)(idx % W_);
            float ys = (float)(idx / W_);
            float vx = vp[(lab*3 + 0)*HW_ + idx];
            float vy = vp[(lab*3 + 1)*HW_ + idx];
            float vz = vp[(lab*3 + 2)*HW_ + idx];
            float nrm = sqrtf(vx*vx + vy*vy) + EPSV_;
            float nx = vx / nrm, ny = vy / nrm;
            float depth = expf(vz);
            int pos = atomicAdd(&s_off[lab], 1);
            // dot(gx,gy) = gx*nx + gy*ny + bconst, bconst = -(xs*nx + ys*ny)
            a4[pos] = make_float4(nx, ny, -(xs*nx + ys*ny), depth);
            a2[pos] = make_float2(xs, ys);
        }
    }
}

// ---------------- Kernel 2: Hough voting ----------------
// grid: (HW/64, B), block: 256. Thread t: L = bx*64 + (t>>2), pixel chunk = t&3.
__global__ __launch_bounds__(256) void k_vote(
    const float4* __restrict__ arr4, const float2* __restrict__ arr2,
    const int* __restrict__ clsStart, ull* __restrict__ best)
{
    int b = blockIdx.y;
    const float4* a4 = arr4 + (size_t)b * P_;
    const float2* a2 = arr2 + (size_t)b * P_;

    __shared__ float4 s4[P_];        // nx, ny, bconst, depth   (38400 B)
    __shared__ float2 s2[P_];        // xs, ys                  (19200 B)
    __shared__ int s_start[NC_ + 1];
    __shared__ ull s_best[NC_];

    int t = threadIdx.x;
    if (t < NC_ + 1) s_start[t] = clsStart[b*(NC_+1) + t];
    if (t < NC_) s_best[t] = 0ULL;
    __syncthreads();
    int nv = s_start[NC_];
    for (int i = t; i < nv; i += 256) { s4[i] = a4[i]; s2[i] = a2[i]; }
    __syncthreads();

    int L = blockIdx.x * 64 + (t >> 2);
    int chunk = t & 3;
    float gx = (float)(L % W_), gy = (float)(L / W_);

    int   cnt[NC_];
    float ds[NC_];
    #pragma unroll
    for (int c = 0; c < NC_; ++c) {
        int lo = s_start[c], hi = s_start[c+1];
        int cc = 0; float dd = 0.f;
        for (int j = lo + chunk; j < hi; j += 4) {
            float4 a = s4[j];
            float2 e = s2[j];
            float dot = fmaf(gx, a.x, fmaf(gy, a.y, a.z));
            float dx = gx - e.x, dy = gy - e.y;
            float d2 = fmaf(dx, dx, dy*dy);
            bool in = (dot > 0.f) && (dot*dot > THR2_ * d2);
            cc += in ? 1 : 0;
            dd += in ? a.w : 0.f;
        }
        cnt[c] = cc; ds[c] = dd;
    }
    // combine the 4 pixel-chunks (adjacent lanes share L)
    #pragma unroll
    for (int c = 0; c < NC_; ++c) {
        cnt[c] += __shfl_xor(cnt[c], 1);
        cnt[c] += __shfl_xor(cnt[c], 2);
        ds[c]  += __shfl_xor(ds[c], 1);
        ds[c]  += __shfl_xor(ds[c], 2);
    }
    if (chunk == 0) {
        #pragma unroll
        for (int c = 0; c < NC_; ++c) {
            // key: votes (<=2400, 12 bits) << 15 | (HW-1-L): max key == argmax w/ lowest-L tiebreak
            unsigned key = ((unsigned)cnt[c] << 15) | (unsigned)(HW_ - 1 - L);
            ull packed = ((ull)key << 32) | (ull)__float_as_uint(ds[c]);
            atomicMax(&s_best[c], packed);
        }
    }
    __syncthreads();
    if (t < NC_) atomicMax(&best[b*NC_ + t], s_best[t]);
}

// ---------------- Kernel 3: finalize boxes + poses ----------------
__global__ void k_final(const ull* __restrict__ best, const int* __restrict__ clsStart,
                        const float* __restrict__ extents, const float* __restrict__ poses,
                        const float* __restrict__ meta, float* __restrict__ out, int B)
{
    int t = blockIdx.x * blockDim.x + threadIdx.x;
    if (t >= B * NC_) return;
    int b = t / NC_, c = t % NC_;
    ull pk = best[t];
    unsigned key = (unsigned)(pk >> 32);
    int L = (HW_ - 1) - (int)(key & 0x7FFFu);
    float vmax = (float)(key >> 15);
    float dsum = __uint_as_float((unsigned)(pk & 0xFFFFFFFFull));
    float nvalid = (float)(clsStart[b*(NC_+1) + c + 1] - clsStart[b*(NC_+1) + c]);
    float dbar = dsum / fmaxf(vmax, 1.0f);
    float cx = (float)(L % W_), cy = (float)(L / W_);
    float fx = meta[b*9 + 0], px = meta[b*9 + 2];
    float fy = meta[b*9 + 4], py = meta[b*9 + 5];
    float e0 = extents[c*3 + 0], e1 = extents[c*3 + 1], e2 = extents[c*3 + 2];
    float diag = sqrtf(e0*e0 + e1*e1 + e2*e2);
    float safe_d = fmaxf(dbar, EPSV_);
    float bw = diag * fx / safe_d;
    float bh = diag * fy / safe_d;
    float score = vmax / fmaxf(nvalid, 1.0f);

    float* ob = out + (size_t)t * 7;
    ob[0] = (float)b;
    ob[1] = (float)c;
    ob[2] = cx - bw * 0.5f;
    ob[3] = cy - bh * 0.5f;
    ob[4] = cx + bw * 0.5f;
    ob[5] = cy + bh * 0.5f;
    ob[6] = score;

    float* op = out + (size_t)B * NC_ * 7 + (size_t)t * 7;
    op[0] = poses[t*7 + 0];
    op[1] = poses[t*7 + 1];
    op[2] = poses[t*7 + 2];
    op[3] = poses[t*7 + 3];
    float tx = (cx - px) * dbar / fmaxf(fx, EPSV_);
    float ty = (cy - py) * dbar / fmaxf(fy, EPSV_);
    op[4] = tx; op[5] = ty;
    op[6] = dbar;
}

extern "C" void kernel_launch(void* const* d_in, const int* in_sizes, int n_in,
                              void* d_out, int out_size, void* d_ws, size_t ws_size,
                              hipStream_t stream)
{
    const int*   labels  = (const int*)d_in[0];
    const int*   masks   = (const int*)d_in[1];
    const float* vp      = (const float*)d_in[2];
    const float* extents = (const float*)d_in[3];
    const float* poses   = (const float*)d_in[4];
    const float* meta    = (const float*)d_in[5];
    int B = in_sizes[0] / HW_;

    // workspace layout (8B-aligned first)
    ull*    best     = (ull*)d_ws;                           // B*NC
    float4* arr4     = (float4*)(best + (size_t)B * NC_);    // B*P float4
    float2* arr2     = (float2*)(arr4 + (size_t)B * P_);     // B*P float2
    int*    clsStart = (int*)(arr2 + (size_t)B * P_);        // B*(NC+1)
    float*  out      = (float*)d_out;

    k_prep<<<B, 256, 0, stream>>>(labels, masks, vp, best, arr4, arr2, clsStart);
    k_vote<<<dim3(HW_/64, B), 256, 0, stream>>>(arr4, arr2, clsStart, best);
    k_final<<<(B*NC_ + 255)/256, 256, 0, stream>>>(best, clsStart, extents, poses, meta, out, B);
}

// Round 2
// 97.922 us; speedup vs baseline: 1.1774x; 1.1774x over previous
//
#include <hip/hip_runtime.h>
#include <hip/hip_fp16.h>
#include <stdint.h>

#define H_ 120
#define W_ 160
#define HW_ (H_*W_)          // 19200
#define SKIP_ 8
#define P_ (HW_/SKIP_)       // 2400 voting pixels
#define NC_ 8                // classes
#define PADCAP_ (P_ + NC_*16) // 2528: per-class segments padded to mult of 16
#define THR2_ 0.81f          // 0.9^2
#define EPSV_ 1e-6f
#define LPB_ 32              // Hough locations per block in k_vote
#define NBLK_ (HW_/LPB_)     // 600 blocks per batch image

typedef unsigned long long ull;

// ---------------- Kernel 1: preprocess + class-compact voting pixels ----------------
// Packs per valid pixel: float4(nx, ny, half2(xs,ys), depth). Segments grouped by
// class, each padded to a multiple of 16 with zeros (nx=ny=0 -> dot=0 -> never inlier).
__global__ __launch_bounds__(1024) void k_prep(
    const int* __restrict__ labels, const int* __restrict__ masks,
    const float* __restrict__ vp,
    ull* __restrict__ best, unsigned* __restrict__ ctr,
    float4* __restrict__ arr4, int* __restrict__ clsStartPad,
    int* __restrict__ nvalid)
{
    int b = blockIdx.x;
    labels += (size_t)b * HW_;
    masks  += (size_t)b * HW_;
    vp     += (size_t)b * 3 * NC_ * HW_;
    float4* a4 = arr4 + (size_t)b * PADCAP_;

    __shared__ int s_cnt[NC_];
    __shared__ int s_off[NC_];
    __shared__ int s_start[NC_ + 1];
    int t = threadIdx.x;
    if (t < NC_) s_cnt[t] = 0;
    // zero whole padded array (pad slots must be "never-inlier")
    float4 z4 = make_float4(0.f, 0.f, 0.f, 0.f);
    for (int i = t; i < PADCAP_; i += 1024) a4[i] = z4;
    __syncthreads();
    for (int p = t; p < P_; p += 1024) {
        int idx = p * SKIP_;
        int lab = labels[idx];
        if (masks[idx] > 0 && lab > 0) atomicAdd(&s_cnt[lab], 1);
    }
    __syncthreads();
    if (t == 0) {
        int acc = 0;
        for (int c = 0; c < NC_; ++c) { s_start[c] = acc; acc += (s_cnt[c] + 15) & ~15; }
        s_start[NC_] = acc;
    }
    __syncthreads();
    if (t < NC_) s_off[t] = s_start[t];
    if (t < NC_ + 1) clsStartPad[b*(NC_+1) + t] = s_start[t];
    if (t < NC_) nvalid[b*NC_ + t] = s_cnt[t];     // true (unpadded) per-class voter count
    if (t < NC_) best[b*NC_ + t] = 0ULL;           // init for atomicMax
    if (b == 0 && t == 0) *ctr = 0u;               // last-block counter
    __syncthreads();
    for (int p = t; p < P_; p += 1024) {
        int idx = p * SKIP_;
        int lab = labels[idx];
        if (masks[idx] > 0 && lab > 0) {
            int xi = idx % W_, yi = idx / W_;
            float xs = (float)xi, ys = (float)yi;
            float vx = vp[(lab*3 + 0)*HW_ + idx];
            float vy = vp[(lab*3 + 1)*HW_ + idx];
            float vz = vp[(lab*3 + 2)*HW_ + idx];
            float nrm = sqrtf(vx*vx + vy*vy) + EPSV_;
            float nx = vx / nrm, ny = vy / nrm;
            float depth = expf(vz);
            unsigned hx = __half_as_ushort(__float2half_rn(xs));  // exact: ints < 2048
            unsigned hy = __half_as_ushort(__float2half_rn(ys));
            int pos = atomicAdd(&s_off[lab], 1);
            a4[pos] = make_float4(nx, ny, __uint_as_float(hx | (hy << 16)), depth);
        }
    }
}

// ---------------- Kernel 2: Hough voting + fused finalize ----------------
// grid: (NBLK_, B), block 256. Thread t: L = bx*32 + (t>>3), pixel chunk = t&7.
__global__ __launch_bounds__(256) void k_vote(
    const float4* __restrict__ arr4, const int* __restrict__ clsStartPad,
    const int* __restrict__ nvalid, ull* __restrict__ best, unsigned* __restrict__ ctr,
    const float* __restrict__ extents, const float* __restrict__ poses,
    const float* __restrict__ meta, float* __restrict__ out, int B)
{
    int b = blockIdx.y;
    const float4* a4 = arr4 + (size_t)b * PADCAP_;

    __shared__ float4 s_a[PADCAP_];   // 40448 B -> 3 blocks/CU
    __shared__ int s_start[NC_ + 1];
    __shared__ ull s_best[NC_];
    __shared__ int s_last;

    int t = threadIdx.x;
    if (t < NC_ + 1) s_start[t] = clsStartPad[b*(NC_+1) + t];
    if (t < NC_) s_best[t] = 0ULL;
    __syncthreads();
    int nvp = s_start[NC_];
    for (int i = t; i < nvp; i += 256) s_a[i] = a4[i];
    __syncthreads();

    int L = blockIdx.x * LPB_ + (t >> 3);
    int chunk = t & 7;
    float gx = (float)(L % W_), gy = (float)(L / W_);

    int   cnt[NC_];
    float ds[NC_];
    #pragma unroll
    for (int c = 0; c < NC_; ++c) {
        int lo = s_start[c], hi = s_start[c+1];   // hi-lo is a multiple of 16
        int cc = 0; float dd = 0.f;
        for (int j = lo + chunk; j < hi; j += 16) {
            // two independent evals per step -> 2 ds_read_b128 in flight
            float4 a0 = s_a[j];
            float4 a1 = s_a[j + 8];
            {
                unsigned u = __float_as_uint(a0.z);
                float xs = __half2float(__ushort_as_half((unsigned short)(u & 0xffffu)));
                float ys = __half2float(__ushort_as_half((unsigned short)(u >> 16)));
                float dx = gx - xs, dy = gy - ys;
                float dot = fmaf(dx, a0.x, dy * a0.y);
                float d2  = fmaf(dx, dx, dy * dy);
                bool in = (dot > 0.f) && (dot * dot > THR2_ * d2);
                cc += in ? 1 : 0;
                dd += in ? a0.w : 0.f;
            }
            {
                unsigned u = __float_as_uint(a1.z);
                float xs = __half2float(__ushort_as_half((unsigned short)(u & 0xffffu)));
                float ys = __half2float(__ushort_as_half((unsigned short)(u >> 16)));
                float dx = gx - xs, dy = gy - ys;
                float dot = fmaf(dx, a1.x, dy * a1.y);
                float d2  = fmaf(dx, dx, dy * dy);
                bool in = (dot > 0.f) && (dot * dot > THR2_ * d2);
                cc += in ? 1 : 0;
                dd += in ? a1.w : 0.f;
            }
        }
        cnt[c] = cc; ds[c] = dd;
    }
    // combine the 8 pixel-chunks (lanes t&7 share L)
    #pragma unroll
    for (int c = 0; c < NC_; ++c) {
        cnt[c] += __shfl_xor(cnt[c], 1);
        cnt[c] += __shfl_xor(cnt[c], 2);
        cnt[c] += __shfl_xor(cnt[c], 4);
        ds[c]  += __shfl_xor(ds[c], 1);
        ds[c]  += __shfl_xor(ds[c], 2);
        ds[c]  += __shfl_xor(ds[c], 4);
    }
    // wave-level argmax on packed key, then one LDS atomic per wave per class
    #pragma unroll
    for (int c = 0; c < NC_; ++c) {
        // key: votes (<=2400, 12 bits) << 15 | (HW-1-L): max == argmax w/ lowest-L tiebreak
        unsigned key = ((unsigned)cnt[c] << 15) | (unsigned)(HW_ - 1 - L);
        ull pk = ((ull)key << 32) | (ull)__float_as_uint(ds[c]);
        ull q;
        q = __shfl_xor(pk, 8);  pk = pk > q ? pk : q;
        q = __shfl_xor(pk, 16); pk = pk > q ? pk : q;
        q = __shfl_xor(pk, 32); pk = pk > q ? pk : q;
        if ((t & 63) == 0) atomicMax(&s_best[c], pk);
    }
    __syncthreads();
    if (t < NC_) atomicMax(&best[b*NC_ + t], s_best[t]);
    __syncthreads();

    // ---- last block finalizes boxes + poses ----
    if (t == 0) {
        __threadfence();
        unsigned r = atomicAdd(ctr, 1u);
        s_last = (r == (unsigned)(gridDim.x * gridDim.y) - 1u) ? 1 : 0;
    }
    __syncthreads();
    if (s_last) {
        for (int i = t; i < B * NC_; i += 256) {
            int bb = i / NC_, c = i % NC_;
            ull pk = atomicMax(&best[i], 0ULL);   // coherent device-scope read
            unsigned key = (unsigned)(pk >> 32);
            int Lw = (HW_ - 1) - (int)(key & 0x7FFFu);
            float vmax = (float)(key >> 15);
            float dsum = __uint_as_float((unsigned)(pk & 0xFFFFFFFFull));
            float nv = (float)nvalid[i];
            float dbar = dsum / fmaxf(vmax, 1.0f);
            float cx = (float)(Lw % W_), cy = (float)(Lw / W_);
            float fx = meta[bb*9 + 0], px = meta[bb*9 + 2];
            float fy = meta[bb*9 + 4], py = meta[bb*9 + 5];
            float e0 = extents[c*3 + 0], e1 = extents[c*3 + 1], e2 = extents[c*3 + 2];
            float diag = sqrtf(e0*e0 + e1*e1 + e2*e2);
            float safe_d = fmaxf(dbar, EPSV_);
            float bw = diag * fx / safe_d;
            float bh = diag * fy / safe_d;
            float score = vmax / fmaxf(nv, 1.0f);

            float* ob = out + (size_t)i * 7;
            ob[0] = (float)bb;
            ob[1] = (float)c;
            ob[2] = cx - bw * 0.5f;
            ob[3] = cy - bh * 0.5f;
            ob[4] = cx + bw * 0.5f;
            ob[5] = cy + bh * 0.5f;
            ob[6] = score;

            float* op = out + (size_t)B * NC_ * 7 + (size_t)i * 7;
            op[0] = poses[i*7 + 0];
            op[1] = poses[i*7 + 1];
            op[2] = poses[i*7 + 2];
            op[3] = poses[i*7 + 3];
            op[4] = (cx - px) * dbar / fmaxf(fx, EPSV_);
            op[5] = (cy - py) * dbar / fmaxf(fy, EPSV_);
            op[6] = dbar;
        }
    }
}

extern "C" void kernel_launch(void* const* d_in, const int* in_sizes, int n_in,
                              void* d_out, int out_size, void* d_ws, size_t ws_size,
                              hipStream_t stream)
{
    const int*   labels  = (const int*)d_in[0];
    const int*   masks   = (const int*)d_in[1];
    const float* vp      = (const float*)d_in[2];
    const float* extents = (const float*)d_in[3];
    const float* poses   = (const float*)d_in[4];
    const float* meta    = (const float*)d_in[5];
    int B = in_sizes[0] / HW_;

    // workspace layout (16B-aligned first)
    float4*   arr4     = (float4*)d_ws;                            // B*PADCAP_ float4
    ull*      best     = (ull*)(arr4 + (size_t)B * PADCAP_);       // B*NC ull
    int*      clsStart = (int*)(best + (size_t)B * NC_);           // B*(NC+1) int
    int*      nvalid   = clsStart + (size_t)B * (NC_ + 1);         // B*NC int
    unsigned* ctr      = (unsigned*)(nvalid + (size_t)B * NC_);    // 1
    float*    out      = (float*)d_out;

    k_prep<<<B, 1024, 0, stream>>>(labels, masks, vp, best, ctr, arr4, clsStart, nvalid);
    k_vote<<<dim3(NBLK_, B), 256, 0, stream>>>(arr4, clsStart, nvalid, best, ctr,
                                               extents, poses, meta, out, B);
}